// Round 11
// baseline (635.953 us; speedup 1.0000x reference)
//
#include <hip/hip_runtime.h>
#include <stdint.h>

#define C_HID 128
#define NGRAPH 64
#define COUT 64
#define POOL_S 64     // pool chunks per graph
#define NBLK 256      // edge-chunk blocks for cnt/scat
#define BKT 256       // nodes per bucket
#define NBUK_MAX 512
#define SCAN_CH 4096  // scan elements per block (256 thr x 16)
#define LAYER_BLOCKS 768

typedef short bf16x8 __attribute__((ext_vector_type(8)));
typedef float f32x4 __attribute__((ext_vector_type(4)));

__device__ __forceinline__ unsigned short f2bf(float f){
  unsigned int u = __builtin_bit_cast(unsigned int, f);
  u = u + 0x7FFFu + ((u >> 16) & 1u);   // RNE
  return (unsigned short)(u >> 16);
}
__device__ __forceinline__ float bflo(unsigned int u){
  return __builtin_bit_cast(float, u << 16);
}
__device__ __forceinline__ float bfhi(unsigned int u){
  return __builtin_bit_cast(float, u & 0xFFFF0000u);
}
__device__ __forceinline__ int clampi(int v, int lo, int hi){
  return v < lo ? lo : (v > hi ? hi : v);
}

__global__ void k_zero(float* __restrict__ out, int n){
  int i = blockIdx.x*blockDim.x + threadIdx.x;
  if (i < n) out[i] = 0.f;
}

// ---------- CSR build, pass 1: per-(block,bucket) histogram ----------
__global__ __launch_bounds__(256) void k_cnt(const int* __restrict__ dst,
                                             int* __restrict__ cntg,
                                             int E, int N, int NBUK, int chunk){
  __shared__ int cnt[NBUK_MAX];
  int blk = blockIdx.x, t = threadIdx.x;
  for (int b = t; b < NBUK; b += 256) cnt[b] = 0;
  __syncthreads();
  int e0 = blk*chunk, e1 = min(E, e0 + chunk);
  for (int e = e0 + t; e < e1; e += 256)
    atomicAdd(&cnt[clampi(dst[e], 0, N-1) >> 8], 1);
  __syncthreads();
  for (int b = t; b < NBUK; b += 256)
    cntg[b*NBLK + blk] = cnt[b];          // bucket-major layout for the scan
}

// ---------- pass 2: hierarchical exclusive scan of n counts ----------
__global__ __launch_bounds__(256) void k_scanA(const int* __restrict__ cnt,
                                               int* __restrict__ bsum, int n){
  __shared__ int red[256];
  int blk = blockIdx.x, t = threadIdx.x;
  int base = blk*SCAN_CH + t*16;
  int s = 0;
  #pragma unroll
  for (int j = 0; j < 16; ++j){ int i = base + j; s += (i < n) ? cnt[i] : 0; }
  red[t] = s; __syncthreads();
  for (int off = 128; off > 0; off >>= 1){
    if (t < off) red[t] += red[t + off];
    __syncthreads();
  }
  if (t == 0) bsum[blk] = red[0];
}

// single block; nb <= 256
__global__ __launch_bounds__(256) void k_scanB(const int* __restrict__ bsum,
                                               int* __restrict__ bbase,
                                               int* __restrict__ bases, int nb, int n){
  __shared__ int buf[256];
  int t = threadIdx.x;
  int v = (t < nb) ? bsum[t] : 0;
  buf[t] = v; __syncthreads();
  for (int off = 1; off < 256; off <<= 1){
    int add = (t >= off) ? buf[t-off] : 0;
    __syncthreads();
    buf[t] += add;
    __syncthreads();
  }
  if (t < nb) bbase[t] = buf[t] - v;       // exclusive
  if (t == nb-1) bases[n] = buf[t];        // total == E
}

__global__ __launch_bounds__(256) void k_scanC(const int* __restrict__ cnt,
                                               const int* __restrict__ bbase,
                                               int* __restrict__ bases, int n){
  __shared__ int buf[256];
  int blk = blockIdx.x, t = threadIdx.x;
  int base = blk*SCAN_CH + t*16;
  int loc[16]; int s = 0;
  #pragma unroll
  for (int j = 0; j < 16; ++j){ int i = base + j; loc[j] = (i < n) ? cnt[i] : 0; s += loc[j]; }
  buf[t] = s; __syncthreads();
  for (int off = 1; off < 256; off <<= 1){
    int add = (t >= off) ? buf[t-off] : 0;
    __syncthreads();
    buf[t] += add;
    __syncthreads();
  }
  int run = bbase[blk] + buf[t] - s;       // exclusive prefix for this thread
  #pragma unroll
  for (int j = 0; j < 16; ++j){
    int i = base + j;
    if (i < n) bases[i] = run;
    run += loc[j];
  }
}

// ---------- pass 3: scatter packed records into per-(block,bucket) segments ----------
__global__ __launch_bounds__(256) void k_scat(const int* __restrict__ src,
                                              const int* __restrict__ dst,
                                              const int* __restrict__ bases,
                                              unsigned int* __restrict__ rec,
                                              int E, int N, int NBUK, int chunk){
  __shared__ int cur[NBUK_MAX];
  int blk = blockIdx.x, t = threadIdx.x;
  for (int b = t; b < NBUK; b += 256) cur[b] = bases[b*NBLK + blk];
  __syncthreads();
  int e0 = blk*chunk, e1 = min(E, e0 + chunk);
  for (int e = e0 + t; e < e1; e += 256){
    int d = clampi(dst[e], 0, N-1);
    int s = clampi(src[e], 0, N-1);
    int p = atomicAdd(&cur[d >> 8], 1);    // LDS atomic
    rec[p] = (unsigned int)s | ((unsigned int)(d & 255) << 24);
  }
}

// ---------- pass 4: per-bucket local CSR (offs, dinv, meta) ----------
__global__ __launch_bounds__(256) void k_csr(const unsigned int* __restrict__ rec,
                                             const int* __restrict__ bases,
                                             int* __restrict__ offs, float* __restrict__ dinv,
                                             int* __restrict__ meta, int E, int N, int NBUK){
  __shared__ int cnt[BKT], loff[BKT], cur[BKT];
  int b = blockIdx.x, t = threadIdx.x;
  cnt[t] = 0;
  __syncthreads();
  int r0 = bases[b*NBLK];
  int r1 = (b+1 < NBUK) ? bases[(b+1)*NBLK] : E;
  for (int i = r0 + t; i < r1; i += 256)
    atomicAdd(&cnt[rec[i] >> 24], 1);
  __syncthreads();
  loff[t] = cnt[t];
  __syncthreads();
  for (int off = 1; off < BKT; off <<= 1){
    int add = (t >= off) ? loff[t - off] : 0;
    __syncthreads();
    loff[t] += add;
    __syncthreads();
  }
  int excl = loff[t] - cnt[t];
  cur[t] = r0 + excl;
  int node = b*BKT + t;
  if (node < N){
    offs[node] = r0 + excl;
    dinv[node] = rsqrtf((float)(cnt[t] + 1));   // +1 = self loop
  }
  if (b == NBUK-1 && t == 0) offs[N] = E;
  __syncthreads();
  for (int i = r0 + t; i < r1; i += 256){
    unsigned int r = rec[i];
    int p = atomicAdd(&cur[r >> 24], 1);
    meta[p] = (int)(r & 0x00FFFFFFu);
  }
}

// ---------- y0 = dinv * x0, fp32 -> packed bf16; zero row N of BOTH buffers ----------
__global__ void k_xcast(const float2* __restrict__ x, const float* __restrict__ dinv,
                        unsigned int* __restrict__ o, unsigned int* __restrict__ o2, int N){
  int i = blockIdx.x*256 + threadIdx.x;
  int tot = N*64;
  if (i < tot){
    float2 v = x[i];
    float dn = dinv[i >> 6];
    o[i] = (unsigned int)f2bf(v.x*dn) | ((unsigned int)f2bf(v.y*dn) << 16);
  } else if (i < tot + 64){
    o[i] = 0;                       // zero row at index N (gather sink)
    o2[i] = 0;
  }
}

// ---------- W fp32 [128][128] -> Wt bf16 [n][k] (3 weights) ----------
__global__ void k_prep(const float* __restrict__ W1, const float* __restrict__ W2,
                       const float* __restrict__ W3, unsigned short* __restrict__ Wt){
  int idx = blockIdx.x*256 + threadIdx.x;     // grid = 192 blocks
  int w = idx >> 14;                           // 16384 per weight
  int r = idx & 16383;
  int n = r & 127, k = r >> 7;
  const float* W = (w == 0) ? W1 : (w == 1) ? W2 : W3;
  Wt[(size_t)w*16384 + (size_t)n*128 + k] = f2bf(W[k*128 + n]);
}

// ---------- fused layer: out = relu( (dinv.(y_i + sum y_src)) @ W + b ) [* dinv if SC]
// y pre-scaled by dinv (y-form). One wave owns 16 rows of a 64-row tile:
// gather-aggregate each row (scalarized: s_load meta, SGPR-base gathers, tail->zero row N),
// stash bf16 row in LDS, then MFMA those same 16 rows (A-frag row = wv*16+ln ->
// wave-private, NO barriers in the tile loop). W LDS-resident, staged once per block.
template<bool SC>
__global__ __launch_bounds__(256) void k_layer(const unsigned int* __restrict__ y,
                                               const int* __restrict__ offs,
                                               const float* __restrict__ dinv,
                                               const int* __restrict__ meta,
                                               const unsigned short* __restrict__ Wt,
                                               const float* __restrict__ bias,
                                               unsigned short* __restrict__ out, int M){
  __shared__ unsigned short wt[128*136];
  __shared__ unsigned short atile[64*136];
  {
    const uint4* wsrc = (const uint4*)Wt;     // 4096 uint4 (8 shorts each)
    for (int i = threadIdx.x; i < 4096; i += 256){
      uint4 v = wsrc[i];
      int n = i >> 4, kblk = i & 15;
      *(uint4*)&wt[n*136 + kblk*8] = v;
    }
  }
  __syncthreads();

  int wv   = __builtin_amdgcn_readfirstlane(threadIdx.x >> 6);
  int lane = threadIdx.x & 63;
  int q = lane >> 4, ln = lane & 15;
  int tiles = (M + 63) >> 6;

  for (int tile = blockIdx.x; tile < tiles; tile += LAYER_BLOCKS){
    // ---- phase 1: this wave aggregates its 16 rows into atile ----
    for (int rr = 0; rr < 16; ++rr){
      int row = tile*64 + wv*16 + rr;            // uniform
      float ax = 0.f, ay = 0.f;
      if (row < M){
        int e0 = offs[row], e1 = offs[row+1];
        int cnt = e1 - e0;
        const int* mrow = meta + e0;
        unsigned int u0 = y[(size_t)row*64 + lane];   // self loop
        ax = bflo(u0); ay = bfhi(u0);
        for (int e = 0; e < cnt; e += 8){
          int s[8]; unsigned int u[8];
          #pragma unroll
          for (int j = 0; j < 8; ++j){
            int ij = e + j;
            int sj = mrow[ij];                   // uniform -> s_load (junk ok past cnt)
            s[j] = (ij < cnt) ? sj : M;          // tail -> zero row M(==N)
          }
          #pragma unroll
          for (int j = 0; j < 8; ++j)
            u[j] = y[(size_t)s[j]*64 + lane];    // SGPR base + lane offset
          #pragma unroll
          for (int j = 0; j < 8; ++j){
            ax += bflo(u[j]);
            ay += bfhi(u[j]);
          }
        }
        float dn = dinv[row];
        ax *= dn; ay *= dn;
      }
      unsigned int p = (unsigned int)f2bf(ax) | ((unsigned int)f2bf(ay) << 16);
      *(unsigned int*)&atile[(wv*16 + rr)*136 + 2*lane] = p;
    }
    // no barrier: each wave MFMAs only rows wv*16+ln that it just wrote
    // (compiler inserts lgkmcnt waits for the ds dependencies)

    // ---- phase 2: MFMA 16 rows x 128 cols ----
    int m0 = tile*64 + wv*16;
    f32x4 zero = {0.f, 0.f, 0.f, 0.f};
    f32x4 acc[8];
    #pragma unroll
    for (int t = 0; t < 8; ++t) acc[t] = zero;

    #pragma unroll
    for (int kk = 0; kk < 4; ++kk){
      bf16x8 a;
      __builtin_memcpy(&a, &atile[(wv*16 + ln)*136 + kk*32 + q*8], 16);
      #pragma unroll
      for (int t = 0; t < 8; ++t){
        bf16x8 b;
        __builtin_memcpy(&b, &wt[(t*16 + ln)*136 + kk*32 + q*8], 16);
        acc[t] = __builtin_amdgcn_mfma_f32_16x16x32_bf16(a, b, acc[t], 0, 0, 0);
      }
    }
    float sc[4];
    #pragma unroll
    for (int r = 0; r < 4; ++r){
      int row = m0 + q*4 + r;
      sc[r] = (SC && row < M) ? dinv[row] : 1.0f;
    }
    #pragma unroll
    for (int t = 0; t < 8; ++t){
      float bv = bias[t*16 + ln];
      #pragma unroll
      for (int r = 0; r < 4; ++r){
        int row = m0 + q*4 + r;
        if (row < M){
          float v = acc[t][r] + bv;
          v = v > 0.f ? v : 0.f;
          if (SC) v *= sc[r];
          out[(size_t)row*128 + t*16 + ln] = f2bf(v);
        }
      }
    }
    // no barrier: atile rows are wave-private
  }
}

// ---------- pooling ----------
__device__ __forceinline__ int lower_bound_i(const int* arr, int n, int val){
  int lo = 0, hi = n;
  while (lo < hi){ int mid = (lo + hi) >> 1; if (arr[mid] < val) lo = mid + 1; else hi = mid; }
  return lo;
}

__global__ void k_pool(const unsigned int* __restrict__ x, const int* __restrict__ batch,
                       float* __restrict__ partial, int N){
  int g = blockIdx.x / POOL_S, s = blockIdx.x % POOL_S;
  int h = threadIdx.x >> 6;
  int lane = threadIdx.x & 63;
  int rs = clampi(lower_bound_i(batch, N, g), 0, N);
  int re = clampi(lower_bound_i(batch, N, g + 1), rs, N);
  int len = re - rs;
  int a = rs + (int)(((long long)len * s) / POOL_S);
  int b = rs + (int)(((long long)len * (s + 1)) / POOL_S);
  float ax = 0.f, ay = 0.f;
  for (int i = a + h; i < b; i += 2){
    unsigned int u = x[(size_t)i*64 + lane];
    ax += bflo(u);
    ay += bfhi(u);
  }
  float* p = partial + ((size_t)(g*POOL_S + s)*2 + h)*C_HID;
  p[2*lane]   = ax;
  p[2*lane+1] = ay;
}

__global__ void k_final(const float* __restrict__ partial, const int* __restrict__ batch,
                        const float* __restrict__ Wl, const float* __restrict__ bl,
                        float* __restrict__ out, int N){
  __shared__ float sums[C_HID];
  int g = blockIdx.x;
  int t = threadIdx.x;
  float acc = 0.f;
  const float* p = partial + (size_t)g*POOL_S*2*C_HID;
  for (int j = 0; j < POOL_S*2; ++j)
    acc += p[j*C_HID + t];
  sums[t] = acc;
  __syncthreads();
  if (t < COUT){
    int rs = clampi(lower_bound_i(batch, N, g), 0, N);
    int re = clampi(lower_bound_i(batch, N, g + 1), rs, N);
    float inv = 1.0f / fmaxf((float)(re - rs), 1.0f);
    float o = 0.f;
    for (int k = 0; k < 128; ++k)
      o += sums[k] * Wl[k*COUT + t];
    out[g*COUT + t] = o * inv + bl[t];
  }
}

extern "C" void kernel_launch(void* const* d_in, const int* in_sizes, int n_in,
                              void* d_out, int out_size, void* d_ws, size_t ws_size,
                              hipStream_t stream){
  const float* x0 = (const float*)d_in[0];
  const int* ei   = (const int*)d_in[1];
  const int* batch= (const int*)d_in[2];
  const float* W1 = (const float*)d_in[3];
  const float* b1 = (const float*)d_in[4];
  const float* W2 = (const float*)d_in[5];
  const float* b2 = (const float*)d_in[6];
  const float* W3 = (const float*)d_in[7];
  const float* b3 = (const float*)d_in[8];
  const float* Wl = (const float*)d_in[9];
  const float* bl = (const float*)d_in[10];
  float* out = (float*)d_out;

  int E = in_sizes[1] / 2;
  int N = in_sizes[2];
  const int* src = ei;
  const int* dst = ei + E;
  int NBUK = (N + BKT - 1) / BKT;
  int chunk = (E + NBLK - 1) / NBLK;
  int ncnt = NBUK * NBLK;
  int nsb  = (ncnt + SCAN_CH - 1) / SCAN_CH;   // scan blocks

  size_t off_acc = 0;
  auto carve = [&](size_t bytes)->size_t{
    size_t r = off_acc; off_acc += (bytes + 255) & ~(size_t)255; return r;
  };
  size_t part_bytes = (size_t)NGRAPH*POOL_S*2*C_HID*4;      // 4 MB
  size_t rec_bytes  = (size_t)E*4;                          // 6.4 MB
  size_t o_cnt   = carve((size_t)ncnt*4);
  size_t o_bases = carve((size_t)(ncnt+1)*4);
  size_t o_bsum  = carve(256*4);
  size_t o_bbase = carve(256*4);
  size_t o_offs  = carve((size_t)(N+1)*4);
  size_t o_dinv  = carve((size_t)N*4);
  size_t o_meta  = carve((size_t)E*4);                      // compact CSR src list
  size_t o_u     = carve(rec_bytes > part_bytes ? rec_bytes : part_bytes); // rec/part union
  size_t o_bufA  = carve((size_t)(N+1)*C_HID*2);            // bf16 ping (+ zero row N)
  size_t o_bufB  = carve((size_t)(N+1)*C_HID*2);            // bf16 pong (+ zero row N)
  size_t o_wt    = carve((size_t)3*128*128*2);              // bf16 Wt x3
  size_t need = off_acc;

  if (ws_size < need || NBUK > NBUK_MAX || nsb > 256){
    k_zero<<<(out_size+255)/256, 256, 0, stream>>>(out, out_size);
    return;
  }

  char* base = (char*)d_ws;
  int* cntg  = (int*)(base + o_cnt);
  int* bases = (int*)(base + o_bases);
  int* bsum  = (int*)(base + o_bsum);
  int* bbase = (int*)(base + o_bbase);
  int* offs  = (int*)(base + o_offs);
  float* dinv= (float*)(base + o_dinv);
  int* meta  = (int*)(base + o_meta);
  unsigned int* rec  = (unsigned int*)(base + o_u);
  float* part        = (float*)(base + o_u);                // aliased (disjoint lifetime)
  unsigned int* bufA = (unsigned int*)(base + o_bufA);
  unsigned int* bufB = (unsigned int*)(base + o_bufB);
  unsigned short* wt = (unsigned short*)(base + o_wt);

  k_cnt  <<<NBLK, 256, 0, stream>>>(dst, cntg, E, N, NBUK, chunk);
  k_scanA<<<nsb, 256, 0, stream>>>(cntg, bsum, ncnt);
  k_scanB<<<1, 256, 0, stream>>>(bsum, bbase, bases, nsb, ncnt);
  k_scanC<<<nsb, 256, 0, stream>>>(cntg, bbase, bases, ncnt);
  k_scat <<<NBLK, 256, 0, stream>>>(src, dst, bases, rec, E, N, NBUK, chunk);
  k_csr  <<<NBUK, BKT, 0, stream>>>(rec, bases, offs, dinv, meta, E, N, NBUK);

  k_xcast<<<(N*64 + 64 + 255)/256, 256, 0, stream>>>((const float2*)x0, dinv, bufA, bufB, N);
  k_prep <<<192, 256, 0, stream>>>(W1, W2, W3, wt);

  // fused spmm+gemm layers: A -> B -> A -> B
  k_layer<true ><<<LAYER_BLOCKS, 256, 0, stream>>>(bufA, offs, dinv, meta, wt,           b1, (unsigned short*)bufB, N);
  k_layer<true ><<<LAYER_BLOCKS, 256, 0, stream>>>(bufB, offs, dinv, meta, wt + 16384,   b2, (unsigned short*)bufA, N);
  k_layer<false><<<LAYER_BLOCKS, 256, 0, stream>>>(bufA, offs, dinv, meta, wt + 2*16384, b3, (unsigned short*)bufB, N);

  k_pool <<<NGRAPH*POOL_S, 128, 0, stream>>>(bufB, batch, part, N);
  k_final<<<NGRAPH, 128, 0, stream>>>(part, batch, Wl, bl, out, N);
}

// Round 12
// 446.711 us; speedup vs baseline: 1.4236x; 1.4236x over previous
//
#include <hip/hip_runtime.h>
#include <stdint.h>

#define C_HID 128
#define NGRAPH 64
#define COUT 64
#define POOL_S 64     // pool chunks per graph
#define NBLK 256      // edge-chunk blocks for cnt/scat
#define BKT 256       // nodes per bucket
#define NBUK_MAX 512
#define SCAN_CH 4096  // scan elements per block (256 thr x 16)

typedef short bf16x8 __attribute__((ext_vector_type(8)));
typedef float f32x4 __attribute__((ext_vector_type(4)));

__device__ __forceinline__ unsigned short f2bf(float f){
  unsigned int u = __builtin_bit_cast(unsigned int, f);
  u = u + 0x7FFFu + ((u >> 16) & 1u);   // RNE
  return (unsigned short)(u >> 16);
}
__device__ __forceinline__ float bflo(unsigned int u){
  return __builtin_bit_cast(float, u << 16);
}
__device__ __forceinline__ float bfhi(unsigned int u){
  return __builtin_bit_cast(float, u & 0xFFFF0000u);
}
__device__ __forceinline__ int clampi(int v, int lo, int hi){
  return v < lo ? lo : (v > hi ? hi : v);
}

__global__ void k_zero(float* __restrict__ out, int n){
  int i = blockIdx.x*blockDim.x + threadIdx.x;
  if (i < n) out[i] = 0.f;
}

// ---------- CSR build, pass 1: per-(block,bucket) histogram ----------
__global__ __launch_bounds__(256) void k_cnt(const int* __restrict__ dst,
                                             int* __restrict__ cntg,
                                             int E, int N, int NBUK, int chunk){
  __shared__ int cnt[NBUK_MAX];
  int blk = blockIdx.x, t = threadIdx.x;
  for (int b = t; b < NBUK; b += 256) cnt[b] = 0;
  __syncthreads();
  int e0 = blk*chunk, e1 = min(E, e0 + chunk);
  for (int e = e0 + t; e < e1; e += 256)
    atomicAdd(&cnt[clampi(dst[e], 0, N-1) >> 8], 1);
  __syncthreads();
  for (int b = t; b < NBUK; b += 256)
    cntg[b*NBLK + blk] = cnt[b];          // bucket-major layout for the scan
}

// ---------- pass 2: hierarchical exclusive scan of n counts ----------
__global__ __launch_bounds__(256) void k_scanA(const int* __restrict__ cnt,
                                               int* __restrict__ bsum, int n){
  __shared__ int red[256];
  int blk = blockIdx.x, t = threadIdx.x;
  int base = blk*SCAN_CH + t*16;
  int s = 0;
  #pragma unroll
  for (int j = 0; j < 16; ++j){ int i = base + j; s += (i < n) ? cnt[i] : 0; }
  red[t] = s; __syncthreads();
  for (int off = 128; off > 0; off >>= 1){
    if (t < off) red[t] += red[t + off];
    __syncthreads();
  }
  if (t == 0) bsum[blk] = red[0];
}

// single block; nb <= 256
__global__ __launch_bounds__(256) void k_scanB(const int* __restrict__ bsum,
                                               int* __restrict__ bbase,
                                               int* __restrict__ bases, int nb, int n){
  __shared__ int buf[256];
  int t = threadIdx.x;
  int v = (t < nb) ? bsum[t] : 0;
  buf[t] = v; __syncthreads();
  for (int off = 1; off < 256; off <<= 1){
    int add = (t >= off) ? buf[t-off] : 0;
    __syncthreads();
    buf[t] += add;
    __syncthreads();
  }
  if (t < nb) bbase[t] = buf[t] - v;       // exclusive
  if (t == nb-1) bases[n] = buf[t];        // total == E
}

__global__ __launch_bounds__(256) void k_scanC(const int* __restrict__ cnt,
                                               const int* __restrict__ bbase,
                                               int* __restrict__ bases, int n){
  __shared__ int buf[256];
  int blk = blockIdx.x, t = threadIdx.x;
  int base = blk*SCAN_CH + t*16;
  int loc[16]; int s = 0;
  #pragma unroll
  for (int j = 0; j < 16; ++j){ int i = base + j; loc[j] = (i < n) ? cnt[i] : 0; s += loc[j]; }
  buf[t] = s; __syncthreads();
  for (int off = 1; off < 256; off <<= 1){
    int add = (t >= off) ? buf[t-off] : 0;
    __syncthreads();
    buf[t] += add;
    __syncthreads();
  }
  int run = bbase[blk] + buf[t] - s;       // exclusive prefix for this thread
  #pragma unroll
  for (int j = 0; j < 16; ++j){
    int i = base + j;
    if (i < n) bases[i] = run;
    run += loc[j];
  }
}

// ---------- pass 3: scatter packed records into per-(block,bucket) segments ----------
__global__ __launch_bounds__(256) void k_scat(const int* __restrict__ src,
                                              const int* __restrict__ dst,
                                              const int* __restrict__ bases,
                                              unsigned int* __restrict__ rec,
                                              int E, int N, int NBUK, int chunk){
  __shared__ int cur[NBUK_MAX];
  int blk = blockIdx.x, t = threadIdx.x;
  for (int b = t; b < NBUK; b += 256) cur[b] = bases[b*NBLK + blk];
  __syncthreads();
  int e0 = blk*chunk, e1 = min(E, e0 + chunk);
  for (int e = e0 + t; e < e1; e += 256){
    int d = clampi(dst[e], 0, N-1);
    int s = clampi(src[e], 0, N-1);
    int p = atomicAdd(&cur[d >> 8], 1);    // LDS atomic
    rec[p] = (unsigned int)s | ((unsigned int)(d & 255) << 24);
  }
}

// ---------- pass 4: per-bucket local CSR (offs, dinv, meta) ----------
__global__ __launch_bounds__(256) void k_csr(const unsigned int* __restrict__ rec,
                                             const int* __restrict__ bases,
                                             int* __restrict__ offs, float* __restrict__ dinv,
                                             int* __restrict__ meta, int E, int N, int NBUK){
  __shared__ int cnt[BKT], loff[BKT], cur[BKT];
  int b = blockIdx.x, t = threadIdx.x;
  cnt[t] = 0;
  __syncthreads();
  int r0 = bases[b*NBLK];
  int r1 = (b+1 < NBUK) ? bases[(b+1)*NBLK] : E;
  for (int i = r0 + t; i < r1; i += 256)
    atomicAdd(&cnt[rec[i] >> 24], 1);
  __syncthreads();
  loff[t] = cnt[t];
  __syncthreads();
  for (int off = 1; off < BKT; off <<= 1){
    int add = (t >= off) ? loff[t - off] : 0;
    __syncthreads();
    loff[t] += add;
    __syncthreads();
  }
  int excl = loff[t] - cnt[t];
  cur[t] = r0 + excl;
  int node = b*BKT + t;
  if (node < N){
    offs[node] = r0 + excl;
    dinv[node] = rsqrtf((float)(cnt[t] + 1));   // +1 = self loop
  }
  if (b == NBUK-1 && t == 0) offs[N] = E;
  __syncthreads();
  for (int i = r0 + t; i < r1; i += 256){
    unsigned int r = rec[i];
    int p = atomicAdd(&cur[r >> 24], 1);
    meta[p] = (int)(r & 0x00FFFFFFu);
  }
}

// ---------- y0 = dinv * x0, fp32 -> packed bf16; zero row N of BOTH buffers ----------
__global__ void k_xcast(const float2* __restrict__ x, const float* __restrict__ dinv,
                        unsigned int* __restrict__ o, unsigned int* __restrict__ o2, int N){
  int i = blockIdx.x*256 + threadIdx.x;
  int tot = N*64;
  if (i < tot){
    float2 v = x[i];
    float dn = dinv[i >> 6];
    o[i] = (unsigned int)f2bf(v.x*dn) | ((unsigned int)f2bf(v.y*dn) << 16);
  } else if (i < tot + 64){
    o[i] = 0;                       // zero row at index N (gather sink)
    o2[i] = 0;
  }
}

// ---------- W fp32 [128][128] -> Wt bf16 [n][k] (3 weights) ----------
__global__ void k_prep(const float* __restrict__ W1, const float* __restrict__ W2,
                       const float* __restrict__ W3, unsigned short* __restrict__ Wt){
  int idx = blockIdx.x*256 + threadIdx.x;     // grid = 192 blocks
  int w = idx >> 14;                           // 16384 per weight
  int r = idx & 16383;
  int n = r & 127, k = r >> 7;
  const float* W = (w == 0) ? W1 : (w == 1) ? W2 : W3;
  Wt[(size_t)w*16384 + (size_t)n*128 + k] = f2bf(W[k*128 + n]);
}

// ---------- SpMM: agg[i] = dinv[i] * ( y[i] + sum_e y[src_e] ) ----------
// XCD channel-half split: block handles (8-node window, channel half).
// half = (blockIdx&7)>>2 -> with round-robin block->XCD mapping, XCDs 0-3 touch
// only lines 0-1 of each feature row, XCDs 4-7 only lines 2-3 -> per-XCD L2
// working set halves. Wave = 2 nodes x 1 half: lanes 0-31 node a, 32-63 node b.
// Meta reads stay wave-uniform s_loads (both rows); per-lane v_cndmask picks src.
__global__ void k_spmm(const unsigned int* __restrict__ y, const int* __restrict__ offs,
                       const float* __restrict__ dinv, const int* __restrict__ meta,
                       unsigned int* __restrict__ agg, int N){
  int t = threadIdx.x;
  int wv    = __builtin_amdgcn_readfirstlane(t >> 6);
  int lane  = t & 63;
  int hlane = lane & 31;          // uint index within the 32-uint half-row
  int hi    = lane >> 5;          // 0 -> node a, 1 -> node b
  int b   = blockIdx.x;
  int half = (b >> 2) & 1;        // channel half (uniform per block)
  int win  = ((b >> 3) * 4 + (b & 3)) * 8;   // 8-node window base
  int nA = win + wv*2;
  int nB = nA + 1;
  if (nA >= N) return;
  bool haveB = (nB < N);
  int e0A = offs[nA], cntA = offs[nA+1] - e0A;
  int e0B = haveB ? offs[nB] : 0;
  int cntB = haveB ? (offs[nB+1] - e0B) : 0;
  const int* mA = meta + e0A;
  const int* mB = meta + e0B;
  float dnA = dinv[nA];
  float dnB = haveB ? dinv[nB] : 0.f;
  int cmax = cntA > cntB ? cntA : cntB;

  int myNode  = hi ? nB : nA;
  int selfRow = (hi && !haveB) ? N : myNode;
  int coff = half*32 + hlane;     // uint offset within a row

  float ax, ay;
  { unsigned int u = y[(size_t)selfRow*64 + coff];   // self loop (y dinv-scaled)
    ax = bflo(u); ay = bfhi(u); }

  for (int e = 0; e < cmax; e += 8){
    int sA[8], sB[8]; unsigned int u[8];
    #pragma unroll
    for (int j = 0; j < 8; ++j){
      int ij = e + j;
      int vA = mA[ij];                          // uniform s_load (junk ok past cnt)
      int vB = mB[ij];
      sA[j] = (ij < cntA) ? vA : N;             // tail -> zero row
      sB[j] = (ij < cntB) ? vB : N;
    }
    #pragma unroll
    for (int j = 0; j < 8; ++j){
      int s = hi ? sB[j] : sA[j];               // v_cndmask
      u[j] = y[(size_t)s*64 + coff];
    }
    #pragma unroll
    for (int j = 0; j < 8; ++j){
      ax += bflo(u[j]);
      ay += bfhi(u[j]);
    }
  }
  float dn = hi ? dnB : dnA;
  ax *= dn; ay *= dn;
  if (!(hi && !haveB))
    agg[(size_t)myNode*64 + coff] = (unsigned int)f2bf(ax) | ((unsigned int)f2bf(ay) << 16);
}

// ---------- GEMM: out = relu(A[Mx128] @ W + b) [* dinv[row] if SC] ----------
#define GEMM_BLOCKS 512
template<bool SC>
__global__ __launch_bounds__(256) void k_gemm(const unsigned short* __restrict__ A,
                                              const unsigned short* __restrict__ Wt,
                                              const float* __restrict__ bias,
                                              const float* __restrict__ scale,
                                              unsigned short* __restrict__ out, int M){
  __shared__ unsigned short wt[128*136];
  {
    const uint4* wsrc = (const uint4*)Wt;     // 4096 uint4 (8 shorts each)
    for (int i = threadIdx.x; i < 4096; i += 256){
      uint4 v = wsrc[i];
      int n = i >> 4, kblk = i & 15;          // row = 16 uint4
      *(uint4*)&wt[n*136 + kblk*8] = v;
    }
  }
  __syncthreads();

  int wv = threadIdx.x >> 6, lane = threadIdx.x & 63;
  int q = lane >> 4, ln = lane & 15;
  int tiles = (M + 63) >> 6;

  for (int tile = blockIdx.x; tile < tiles; tile += GEMM_BLOCKS){
    int m0 = tile*64 + wv*16;
    int arow = m0 + ln;
    bool arow_ok = (arow < M);
    int arow_s = arow_ok ? arow : 0;

    f32x4 zero = {0.f, 0.f, 0.f, 0.f};
    f32x4 acc[8];
    #pragma unroll
    for (int t = 0; t < 8; ++t) acc[t] = zero;

    #pragma unroll
    for (int kk = 0; kk < 4; ++kk){
      bf16x8 a;
      if (arow_ok){
        __builtin_memcpy(&a, A + (size_t)arow_s*128 + kk*32 + q*8, 16);
      } else {
        a = (bf16x8){0,0,0,0,0,0,0,0};
      }
      #pragma unroll
      for (int t = 0; t < 8; ++t){
        bf16x8 b;
        __builtin_memcpy(&b, &wt[(t*16 + ln)*136 + kk*32 + q*8], 16);
        acc[t] = __builtin_amdgcn_mfma_f32_16x16x32_bf16(a, b, acc[t], 0, 0, 0);
      }
    }
    float sc[4];
    #pragma unroll
    for (int r = 0; r < 4; ++r){
      int row = m0 + q*4 + r;
      sc[r] = (SC && row < M) ? scale[row] : 1.0f;
    }
    #pragma unroll
    for (int t = 0; t < 8; ++t){
      float bv = bias[t*16 + ln];
      #pragma unroll
      for (int r = 0; r < 4; ++r){
        int row = m0 + q*4 + r;
        if (row < M){
          float v = acc[t][r] + bv;
          v = v > 0.f ? v : 0.f;
          if (SC) v *= sc[r];
          out[(size_t)row*128 + t*16 + ln] = f2bf(v);
        }
      }
    }
  }
}

// ---------- pooling ----------
__device__ __forceinline__ int lower_bound_i(const int* arr, int n, int val){
  int lo = 0, hi = n;
  while (lo < hi){ int mid = (lo + hi) >> 1; if (arr[mid] < val) lo = mid + 1; else hi = mid; }
  return lo;
}

__global__ void k_pool(const unsigned int* __restrict__ x, const int* __restrict__ batch,
                       float* __restrict__ partial, int N){
  int g = blockIdx.x / POOL_S, s = blockIdx.x % POOL_S;
  int h = threadIdx.x >> 6;
  int lane = threadIdx.x & 63;
  int rs = clampi(lower_bound_i(batch, N, g), 0, N);
  int re = clampi(lower_bound_i(batch, N, g + 1), rs, N);
  int len = re - rs;
  int a = rs + (int)(((long long)len * s) / POOL_S);
  int b = rs + (int)(((long long)len * (s + 1)) / POOL_S);
  float ax = 0.f, ay = 0.f;
  for (int i = a + h; i < b; i += 2){
    unsigned int u = x[(size_t)i*64 + lane];
    ax += bflo(u);
    ay += bfhi(u);
  }
  float* p = partial + ((size_t)(g*POOL_S + s)*2 + h)*C_HID;
  p[2*lane]   = ax;
  p[2*lane+1] = ay;
}

__global__ void k_final(const float* __restrict__ partial, const int* __restrict__ batch,
                        const float* __restrict__ Wl, const float* __restrict__ bl,
                        float* __restrict__ out, int N){
  __shared__ float sums[C_HID];
  int g = blockIdx.x;
  int t = threadIdx.x;
  float acc = 0.f;
  const float* p = partial + (size_t)g*POOL_S*2*C_HID;
  for (int j = 0; j < POOL_S*2; ++j)
    acc += p[j*C_HID + t];
  sums[t] = acc;
  __syncthreads();
  if (t < COUT){
    int rs = clampi(lower_bound_i(batch, N, g), 0, N);
    int re = clampi(lower_bound_i(batch, N, g + 1), rs, N);
    float inv = 1.0f / fmaxf((float)(re - rs), 1.0f);
    float o = 0.f;
    for (int k = 0; k < 128; ++k)
      o += sums[k] * Wl[k*COUT + t];
    out[g*COUT + t] = o * inv + bl[t];
  }
}

extern "C" void kernel_launch(void* const* d_in, const int* in_sizes, int n_in,
                              void* d_out, int out_size, void* d_ws, size_t ws_size,
                              hipStream_t stream){
  const float* x0 = (const float*)d_in[0];
  const int* ei   = (const int*)d_in[1];
  const int* batch= (const int*)d_in[2];
  const float* W1 = (const float*)d_in[3];
  const float* b1 = (const float*)d_in[4];
  const float* W2 = (const float*)d_in[5];
  const float* b2 = (const float*)d_in[6];
  const float* W3 = (const float*)d_in[7];
  const float* b3 = (const float*)d_in[8];
  const float* Wl = (const float*)d_in[9];
  const float* bl = (const float*)d_in[10];
  float* out = (float*)d_out;

  int E = in_sizes[1] / 2;
  int N = in_sizes[2];
  const int* src = ei;
  const int* dst = ei + E;
  int NBUK = (N + BKT - 1) / BKT;
  int chunk = (E + NBLK - 1) / NBLK;
  int ncnt = NBUK * NBLK;
  int nsb  = (ncnt + SCAN_CH - 1) / SCAN_CH;   // scan blocks

  size_t off_acc = 0;
  auto carve = [&](size_t bytes)->size_t{
    size_t r = off_acc; off_acc += (bytes + 255) & ~(size_t)255; return r;
  };
  size_t part_bytes = (size_t)NGRAPH*POOL_S*2*C_HID*4;      // 4 MB
  size_t rec_bytes  = (size_t)E*4;                          // 6.4 MB
  size_t o_cnt   = carve((size_t)ncnt*4);
  size_t o_bases = carve((size_t)(ncnt+1)*4);
  size_t o_bsum  = carve(256*4);
  size_t o_bbase = carve(256*4);
  size_t o_offs  = carve((size_t)(N+1)*4);
  size_t o_dinv  = carve((size_t)N*4);
  size_t o_meta  = carve((size_t)E*4);                      // compact CSR src list
  size_t o_u     = carve(rec_bytes > part_bytes ? rec_bytes : part_bytes); // rec/part union
  size_t o_bufA  = carve((size_t)(N+1)*C_HID*2);            // bf16 ping (+ zero row N)
  size_t o_bufB  = carve((size_t)(N+1)*C_HID*2);            // bf16 pong (+ zero row N)
  size_t o_wt    = carve((size_t)3*128*128*2);              // bf16 Wt x3
  size_t need = off_acc;

  if (ws_size < need || NBUK > NBUK_MAX || nsb > 256){
    k_zero<<<(out_size+255)/256, 256, 0, stream>>>(out, out_size);
    return;
  }

  char* base = (char*)d_ws;
  int* cntg  = (int*)(base + o_cnt);
  int* bases = (int*)(base + o_bases);
  int* bsum  = (int*)(base + o_bsum);
  int* bbase = (int*)(base + o_bbase);
  int* offs  = (int*)(base + o_offs);
  float* dinv= (float*)(base + o_dinv);
  int* meta  = (int*)(base + o_meta);
  unsigned int* rec  = (unsigned int*)(base + o_u);
  float* part        = (float*)(base + o_u);                // aliased (disjoint lifetime)
  unsigned int* bufA = (unsigned int*)(base + o_bufA);
  unsigned int* bufB = (unsigned int*)(base + o_bufB);
  unsigned short* wt = (unsigned short*)(base + o_wt);

  k_cnt  <<<NBLK, 256, 0, stream>>>(dst, cntg, E, N, NBUK, chunk);
  k_scanA<<<nsb, 256, 0, stream>>>(cntg, bsum, ncnt);
  k_scanB<<<1, 256, 0, stream>>>(bsum, bbase, bases, nsb, ncnt);
  k_scanC<<<nsb, 256, 0, stream>>>(cntg, bbase, bases, ncnt);
  k_scat <<<NBLK, 256, 0, stream>>>(src, dst, bases, rec, E, N, NBUK, chunk);
  k_csr  <<<NBUK, BKT, 0, stream>>>(rec, bases, offs, dinv, meta, E, N, NBUK);

  k_xcast<<<(N*64 + 64 + 255)/256, 256, 0, stream>>>((const float2*)x0, dinv, bufA, bufB, N);
  k_prep <<<192, 256, 0, stream>>>(W1, W2, W3, wt);

  // spmm grid: 8 blocks per 32-node window (4 windows x 2 channel halves)
  int spmm_grid = 8 * ((N + 31) / 32);

  k_spmm<<<spmm_grid, 256, 0, stream>>>(bufA, offs, dinv, meta, bufB, N);
  k_gemm<true ><<<GEMM_BLOCKS, 256, 0, stream>>>((const unsigned short*)bufB, wt,           b1, dinv, (unsigned short*)bufA, N);
  k_spmm<<<spmm_grid, 256, 0, stream>>>(bufA, offs, dinv, meta, bufB, N);
  k_gemm<true ><<<GEMM_BLOCKS, 256, 0, stream>>>((const unsigned short*)bufB, wt + 16384,   b2, dinv, (unsigned short*)bufA, N);
  k_spmm<<<spmm_grid, 256, 0, stream>>>(bufA, offs, dinv, meta, bufB, N);
  k_gemm<false><<<GEMM_BLOCKS, 256, 0, stream>>>((const unsigned short*)bufB, wt + 2*16384, b3, dinv, (unsigned short*)bufA, N);

  k_pool <<<NGRAPH*POOL_S, 128, 0, stream>>>(bufA, batch, part, N);
  k_final<<<NGRAPH, 128, 0, stream>>>(part, batch, Wl, bl, out, N);
}

// Round 14
// 372.879 us; speedup vs baseline: 1.7055x; 1.1980x over previous
//
#include <hip/hip_runtime.h>
#include <stdint.h>

#define C_HID 128
#define NGRAPH 64
#define COUT 64
#define POOL_S 64     // pool chunks per graph
#define NBLK 256      // edge-chunk blocks for cnt/scat
#define BKT 256       // nodes per bucket
#define NBUK_MAX 512
#define SCAN_CH 4096  // scan elements per block (256 thr x 16)

typedef short bf16x8 __attribute__((ext_vector_type(8)));
typedef float f32x4 __attribute__((ext_vector_type(4)));
typedef float f32x2 __attribute__((ext_vector_type(2)));

__device__ __forceinline__ unsigned short f2bf(float f){
  unsigned int u = __builtin_bit_cast(unsigned int, f);
  u = u + 0x7FFFu + ((u >> 16) & 1u);   // RNE
  return (unsigned short)(u >> 16);
}
__device__ __forceinline__ float bflo(unsigned int u){
  return __builtin_bit_cast(float, u << 16);
}
__device__ __forceinline__ float bfhi(unsigned int u){
  return __builtin_bit_cast(float, u & 0xFFFF0000u);
}
__device__ __forceinline__ int clampi(int v, int lo, int hi){
  return v < lo ? lo : (v > hi ? hi : v);
}

__global__ void k_zero(float* __restrict__ out, int n){
  int i = blockIdx.x*blockDim.x + threadIdx.x;
  if (i < n) out[i] = 0.f;
}

// ---------- CSR build, pass 1: per-(block,bucket) histogram ----------
__global__ __launch_bounds__(256) void k_cnt(const int* __restrict__ dst,
                                             int* __restrict__ cntg,
                                             int E, int N, int NBUK, int chunk){
  __shared__ int cnt[NBUK_MAX];
  int blk = blockIdx.x, t = threadIdx.x;
  for (int b = t; b < NBUK; b += 256) cnt[b] = 0;
  __syncthreads();
  int e0 = blk*chunk, e1 = min(E, e0 + chunk);
  for (int e = e0 + t; e < e1; e += 256)
    atomicAdd(&cnt[clampi(dst[e], 0, N-1) >> 8], 1);
  __syncthreads();
  for (int b = t; b < NBUK; b += 256)
    cntg[b*NBLK + blk] = cnt[b];          // bucket-major layout for the scan
}

// ---------- pass 2: hierarchical exclusive scan of n counts ----------
__global__ __launch_bounds__(256) void k_scanA(const int* __restrict__ cnt,
                                               int* __restrict__ bsum, int n){
  __shared__ int red[256];
  int blk = blockIdx.x, t = threadIdx.x;
  int base = blk*SCAN_CH + t*16;
  int s = 0;
  #pragma unroll
  for (int j = 0; j < 16; ++j){ int i = base + j; s += (i < n) ? cnt[i] : 0; }
  red[t] = s; __syncthreads();
  for (int off = 128; off > 0; off >>= 1){
    if (t < off) red[t] += red[t + off];
    __syncthreads();
  }
  if (t == 0) bsum[blk] = red[0];
}

// single block; nb <= 256
__global__ __launch_bounds__(256) void k_scanB(const int* __restrict__ bsum,
                                               int* __restrict__ bbase,
                                               int* __restrict__ bases, int nb, int n){
  __shared__ int buf[256];
  int t = threadIdx.x;
  int v = (t < nb) ? bsum[t] : 0;
  buf[t] = v; __syncthreads();
  for (int off = 1; off < 256; off <<= 1){
    int add = (t >= off) ? buf[t-off] : 0;
    __syncthreads();
    buf[t] += add;
    __syncthreads();
  }
  if (t < nb) bbase[t] = buf[t] - v;       // exclusive
  if (t == nb-1) bases[n] = buf[t];        // total == E
}

__global__ __launch_bounds__(256) void k_scanC(const int* __restrict__ cnt,
                                               const int* __restrict__ bbase,
                                               int* __restrict__ bases, int n){
  __shared__ int buf[256];
  int blk = blockIdx.x, t = threadIdx.x;
  int base = blk*SCAN_CH + t*16;
  int loc[16]; int s = 0;
  #pragma unroll
  for (int j = 0; j < 16; ++j){ int i = base + j; loc[j] = (i < n) ? cnt[i] : 0; s += loc[j]; }
  buf[t] = s; __syncthreads();
  for (int off = 1; off < 256; off <<= 1){
    int add = (t >= off) ? buf[t-off] : 0;
    __syncthreads();
    buf[t] += add;
    __syncthreads();
  }
  int run = bbase[blk] + buf[t] - s;       // exclusive prefix for this thread
  #pragma unroll
  for (int j = 0; j < 16; ++j){
    int i = base + j;
    if (i < n) bases[i] = run;
    run += loc[j];
  }
}

// ---------- pass 3: scatter packed records into per-(block,bucket) segments ----------
__global__ __launch_bounds__(256) void k_scat(const int* __restrict__ src,
                                              const int* __restrict__ dst,
                                              const int* __restrict__ bases,
                                              unsigned int* __restrict__ rec,
                                              int E, int N, int NBUK, int chunk){
  __shared__ int cur[NBUK_MAX];
  int blk = blockIdx.x, t = threadIdx.x;
  for (int b = t; b < NBUK; b += 256) cur[b] = bases[b*NBLK + blk];
  __syncthreads();
  int e0 = blk*chunk, e1 = min(E, e0 + chunk);
  for (int e = e0 + t; e < e1; e += 256){
    int d = clampi(dst[e], 0, N-1);
    int s = clampi(src[e], 0, N-1);
    int p = atomicAdd(&cur[d >> 8], 1);    // LDS atomic
    rec[p] = (unsigned int)s | ((unsigned int)(d & 255) << 24);
  }
}

// ---------- pass 4: per-bucket local CSR (offs, dinv, meta) ----------
__global__ __launch_bounds__(256) void k_csr(const unsigned int* __restrict__ rec,
                                             const int* __restrict__ bases,
                                             int* __restrict__ offs, float* __restrict__ dinv,
                                             int* __restrict__ meta, int E, int N, int NBUK){
  __shared__ int cnt[BKT], loff[BKT], cur[BKT];
  int b = blockIdx.x, t = threadIdx.x;
  cnt[t] = 0;
  __syncthreads();
  int r0 = bases[b*NBLK];
  int r1 = (b+1 < NBUK) ? bases[(b+1)*NBLK] : E;
  for (int i = r0 + t; i < r1; i += 256)
    atomicAdd(&cnt[rec[i] >> 24], 1);
  __syncthreads();
  loff[t] = cnt[t];
  __syncthreads();
  for (int off = 1; off < BKT; off <<= 1){
    int add = (t >= off) ? loff[t - off] : 0;
    __syncthreads();
    loff[t] += add;
    __syncthreads();
  }
  int excl = loff[t] - cnt[t];
  cur[t] = r0 + excl;
  int node = b*BKT + t;
  if (node < N){
    offs[node] = r0 + excl;
    dinv[node] = rsqrtf((float)(cnt[t] + 1));   // +1 = self loop
  }
  if (b == NBUK-1 && t == 0) offs[N] = E;
  __syncthreads();
  for (int i = r0 + t; i < r1; i += 256){
    unsigned int r = rec[i];
    int p = atomicAdd(&cur[r >> 24], 1);
    meta[p] = (int)(r & 0x00FFFFFFu);
  }
}

// ---------- y0 = 64*dinv*x0, fp32 -> fp8 e4m3; zero row N of BOTH fp8 buffers ----------
// S=64 (exact pow2) keeps y values in e4m3's normal range (~0.1..80).
__global__ void k_xcast(const float2* __restrict__ x, const float* __restrict__ dinv,
                        unsigned short* __restrict__ y, unsigned short* __restrict__ y2, int N){
  int i = blockIdx.x*256 + threadIdx.x;
  int tot = N*64;
  if (i < tot){
    float2 v = x[i];
    float dn = dinv[i >> 6] * 64.f;
    int p = __builtin_amdgcn_cvt_pk_fp8_f32(v.x*dn, v.y*dn, 0, false);
    y[i] = (unsigned short)(p & 0xFFFF);
  } else if (i < tot + 64){
    y[i] = 0;                       // zero row at index N (gather sink)
    y2[i] = 0;
  }
}

// ---------- W fp32 [128][128] -> Wt bf16 [n][k] (3 weights) ----------
__global__ void k_prep(const float* __restrict__ W1, const float* __restrict__ W2,
                       const float* __restrict__ W3, unsigned short* __restrict__ Wt){
  int idx = blockIdx.x*256 + threadIdx.x;     // grid = 192 blocks
  int w = idx >> 14;                           // 16384 per weight
  int r = idx & 16383;
  int n = r & 127, k = r >> 7;
  const float* W = (w == 0) ? W1 : (w == 1) ? W2 : W3;
  Wt[(size_t)w*16384 + (size_t)n*128 + k] = f2bf(W[k*128 + n]);
}

// ---------- SpMM: agg[i] = (dinv[i]/64) * ( y[i] + sum_e y[src_e] ), y fp8 ----------
// wave per node (uniform): meta s_loads, SGPR-base + lane*2B gathers (128B/row).
// fp8 pair -> f32x2 via v_cvt_pk_f32_fp8. Output bf16 packed (GEMM A unchanged).
__global__ void k_spmm(const unsigned short* __restrict__ y, const int* __restrict__ offs,
                       const float* __restrict__ dinv, const int* __restrict__ meta,
                       unsigned int* __restrict__ agg, int N){
  int wv   = __builtin_amdgcn_readfirstlane(threadIdx.x >> 6);
  int lane = threadIdx.x & 63;
  int node = blockIdx.x*4 + wv;
  if (node >= N) return;
  int e0 = offs[node], e1 = offs[node+1];
  int cnt = e1 - e0;
  const int* mrow = meta + e0;

  float ax, ay;
  { f32x2 f = __builtin_amdgcn_cvt_pk_f32_fp8((int)y[(size_t)node*64 + lane], false);
    ax = f.x; ay = f.y; }           // self loop

  for (int e = 0; e < cnt; e += 8){
    int s[8]; unsigned short u[8];
    #pragma unroll
    for (int j = 0; j < 8; ++j){
      int ij = e + j;
      int sj = mrow[ij];                           // uniform -> s_load (junk ok past cnt)
      s[j] = (ij < cnt) ? sj : N;                  // tail -> zero row
    }
    #pragma unroll
    for (int j = 0; j < 8; ++j)
      u[j] = y[(size_t)s[j]*64 + lane];            // SGPR base + lane offset (2B)
    #pragma unroll
    for (int j = 0; j < 8; ++j){
      f32x2 f = __builtin_amdgcn_cvt_pk_f32_fp8((int)u[j], false);
      ax += f.x;
      ay += f.y;
    }
  }
  float dn = dinv[node] * 0.015625f;   // /64
  ax *= dn; ay *= dn;
  agg[(size_t)node*64 + lane] = (unsigned int)f2bf(ax) | ((unsigned int)f2bf(ay) << 16);
}

// ---------- GEMM: h = relu(A[Mx128] @ W + b); FP8OUT: y' = fp8(64*dinv*h), else bf16 h ----
#define GEMM_BLOCKS 512
template<bool FP8OUT>
__global__ __launch_bounds__(256) void k_gemm(const unsigned short* __restrict__ A,
                                              const unsigned short* __restrict__ Wt,
                                              const float* __restrict__ bias,
                                              const float* __restrict__ scale,
                                              void* __restrict__ outv, int M){
  __shared__ unsigned short wt[128*136];
  {
    const uint4* wsrc = (const uint4*)Wt;     // 4096 uint4 (8 shorts each)
    for (int i = threadIdx.x; i < 4096; i += 256){
      uint4 v = wsrc[i];
      int n = i >> 4, kblk = i & 15;          // row = 16 uint4
      *(uint4*)&wt[n*136 + kblk*8] = v;
    }
  }
  __syncthreads();

  int wv = threadIdx.x >> 6, lane = threadIdx.x & 63;
  int q = lane >> 4, ln = lane & 15;
  int tiles = (M + 63) >> 6;

  for (int tile = blockIdx.x; tile < tiles; tile += GEMM_BLOCKS){
    int m0 = tile*64 + wv*16;
    int arow = m0 + ln;
    bool arow_ok = (arow < M);
    int arow_s = arow_ok ? arow : 0;

    f32x4 zero = {0.f, 0.f, 0.f, 0.f};
    f32x4 acc[8];
    #pragma unroll
    for (int t = 0; t < 8; ++t) acc[t] = zero;

    #pragma unroll
    for (int kk = 0; kk < 4; ++kk){
      bf16x8 a;
      if (arow_ok){
        __builtin_memcpy(&a, A + (size_t)arow_s*128 + kk*32 + q*8, 16);
      } else {
        a = (bf16x8){0,0,0,0,0,0,0,0};
      }
      #pragma unroll
      for (int t = 0; t < 8; ++t){
        bf16x8 b;
        __builtin_memcpy(&b, &wt[(t*16 + ln)*136 + kk*32 + q*8], 16);
        acc[t] = __builtin_amdgcn_mfma_f32_16x16x32_bf16(a, b, acc[t], 0, 0, 0);
      }
    }
    float sc[4];
    #pragma unroll
    for (int r = 0; r < 4; ++r){
      int row = m0 + q*4 + r;
      sc[r] = (FP8OUT && row < M) ? scale[row] * 64.f : 1.0f;
    }
    #pragma unroll
    for (int t = 0; t < 8; ++t){
      float bv = bias[t*16 + ln];
      #pragma unroll
      for (int r = 0; r < 4; ++r){
        int row = m0 + q*4 + r;
        if (row < M){
          float v = acc[t][r] + bv;
          v = v > 0.f ? v : 0.f;
          if (FP8OUT){
            v *= sc[r];
            int p = __builtin_amdgcn_cvt_pk_fp8_f32(v, v, 0, false);
            ((unsigned char*)outv)[(size_t)row*128 + t*16 + ln] = (unsigned char)(p & 0xFF);
          } else {
            ((unsigned short*)outv)[(size_t)row*128 + t*16 + ln] = f2bf(v);
          }
        }
      }
    }
  }
}

// ---------- pooling ----------
__device__ __forceinline__ int lower_bound_i(const int* arr, int n, int val){
  int lo = 0, hi = n;
  while (lo < hi){ int mid = (lo + hi) >> 1; if (arr[mid] < val) lo = mid + 1; else hi = mid; }
  return lo;
}

__global__ void k_pool(const unsigned int* __restrict__ x, const int* __restrict__ batch,
                       float* __restrict__ partial, int N){
  int g = blockIdx.x / POOL_S, s = blockIdx.x % POOL_S;
  int h = threadIdx.x >> 6;
  int lane = threadIdx.x & 63;
  int rs = clampi(lower_bound_i(batch, N, g), 0, N);
  int re = clampi(lower_bound_i(batch, N, g + 1), rs, N);
  int len = re - rs;
  int a = rs + (int)(((long long)len * s) / POOL_S);
  int b = rs + (int)(((long long)len * (s + 1)) / POOL_S);
  float ax = 0.f, ay = 0.f;
  for (int i = a + h; i < b; i += 2){
    unsigned int u = x[(size_t)i*64 + lane];
    ax += bflo(u);
    ay += bfhi(u);
  }
  float* p = partial + ((size_t)(g*POOL_S + s)*2 + h)*C_HID;
  p[2*lane]   = ax;
  p[2*lane+1] = ay;
}

__global__ void k_final(const float* __restrict__ partial, const int* __restrict__ batch,
                        const float* __restrict__ Wl, const float* __restrict__ bl,
                        float* __restrict__ out, int N){
  __shared__ float sums[C_HID];
  int g = blockIdx.x;
  int t = threadIdx.x;
  float acc = 0.f;
  const float* p = partial + (size_t)g*POOL_S*2*C_HID;
  for (int j = 0; j < POOL_S*2; ++j)
    acc += p[j*C_HID + t];
  sums[t] = acc;
  __syncthreads();
  if (t < COUT){
    int rs = clampi(lower_bound_i(batch, N, g), 0, N);
    int re = clampi(lower_bound_i(batch, N, g + 1), rs, N);
    float inv = 1.0f / fmaxf((float)(re - rs), 1.0f);
    float o = 0.f;
    for (int k = 0; k < 128; ++k)
      o += sums[k] * Wl[k*COUT + t];
    out[g*COUT + t] = o * inv + bl[t];
  }
}

extern "C" void kernel_launch(void* const* d_in, const int* in_sizes, int n_in,
                              void* d_out, int out_size, void* d_ws, size_t ws_size,
                              hipStream_t stream){
  const float* x0 = (const float*)d_in[0];
  const int* ei   = (const int*)d_in[1];
  const int* batch= (const int*)d_in[2];
  const float* W1 = (const float*)d_in[3];
  const float* b1 = (const float*)d_in[4];
  const float* W2 = (const float*)d_in[5];
  const float* b2 = (const float*)d_in[6];
  const float* W3 = (const float*)d_in[7];
  const float* b3 = (const float*)d_in[8];
  const float* Wl = (const float*)d_in[9];
  const float* bl = (const float*)d_in[10];
  float* out = (float*)d_out;

  int E = in_sizes[1] / 2;
  int N = in_sizes[2];
  const int* src = ei;
  const int* dst = ei + E;
  int NBUK = (N + BKT - 1) / BKT;
  int chunk = (E + NBLK - 1) / NBLK;
  int ncnt = NBUK * NBLK;
  int nsb  = (ncnt + SCAN_CH - 1) / SCAN_CH;   // scan blocks

  size_t off_acc = 0;
  auto carve = [&](size_t bytes)->size_t{
    size_t r = off_acc; off_acc += (bytes + 255) & ~(size_t)255; return r;
  };
  size_t o_cnt   = carve((size_t)ncnt*4);
  size_t o_bases = carve((size_t)(ncnt+1)*4);
  size_t o_bsum  = carve(256*4);
  size_t o_bbase = carve(256*4);
  size_t o_offs  = carve((size_t)(N+1)*4);
  size_t o_dinv  = carve((size_t)N*4);
  size_t o_meta  = carve((size_t)E*4);                      // compact CSR src list
  size_t o_rec   = carve((size_t)E*4);                      // bucket-sorted records
  size_t o_yA    = carve((size_t)(N+1)*C_HID);              // fp8 ping (+ zero row N)
  size_t o_yB    = carve((size_t)(N+1)*C_HID);              // fp8 pong (+ zero row N)
  size_t o_aggb  = carve((size_t)N*C_HID*2);                // bf16 agg
  size_t o_wt    = carve((size_t)3*128*128*2);              // bf16 Wt x3
  size_t need = off_acc;

  // hbuf (bf16 h3, 25.6MB) aliases meta+rec+yA (all dead after spmm3)
  size_t hbuf_avail = o_aggb - o_meta;
  bool alias_ok = hbuf_avail >= (size_t)N*C_HID*2;
  // part (4MB) aliases yB (dead after spmm3); yB region is 12.8MB
  alias_ok = alias_ok &&
             ((size_t)(N+1)*C_HID >= (size_t)NGRAPH*POOL_S*2*C_HID*4);

  if (ws_size < need || NBUK > NBUK_MAX || nsb > 256 || !alias_ok){
    k_zero<<<(out_size+255)/256, 256, 0, stream>>>(out, out_size);
    return;
  }

  char* base = (char*)d_ws;
  int* cntg  = (int*)(base + o_cnt);
  int* bases = (int*)(base + o_bases);
  int* bsum  = (int*)(base + o_bsum);
  int* bbase = (int*)(base + o_bbase);
  int* offs  = (int*)(base + o_offs);
  float* dinv= (float*)(base + o_dinv);
  int* meta  = (int*)(base + o_meta);
  unsigned int* rec   = (unsigned int*)(base + o_rec);
  unsigned short* yA  = (unsigned short*)(base + o_yA);     // fp8 pairs as ushort
  unsigned short* yB  = (unsigned short*)(base + o_yB);
  unsigned int* aggb  = (unsigned int*)(base + o_aggb);
  unsigned short* wt  = (unsigned short*)(base + o_wt);
  unsigned short* hbuf= (unsigned short*)(base + o_meta);   // alias: meta+rec+yA region
  float* part         = (float*)(base + o_yB);              // alias: yB region

  k_cnt  <<<NBLK, 256, 0, stream>>>(dst, cntg, E, N, NBUK, chunk);
  k_scanA<<<nsb, 256, 0, stream>>>(cntg, bsum, ncnt);
  k_scanB<<<1, 256, 0, stream>>>(bsum, bbase, bases, nsb, ncnt);
  k_scanC<<<nsb, 256, 0, stream>>>(cntg, bbase, bases, ncnt);
  k_scat <<<NBLK, 256, 0, stream>>>(src, dst, bases, rec, E, N, NBUK, chunk);
  k_csr  <<<NBUK, BKT, 0, stream>>>(rec, bases, offs, dinv, meta, E, N, NBUK);

  k_xcast<<<(N*64 + 64 + 255)/256, 256, 0, stream>>>((const float2*)x0, dinv, yA, yB, N);
  k_prep <<<192, 256, 0, stream>>>(W1, W2, W3, wt);

  int spmm_grid = (N + 3) / 4;     // 4 waves/block, one wave per node

  k_spmm<<<spmm_grid, 256, 0, stream>>>(yA, offs, dinv, meta, aggb, N);
  k_gemm<true ><<<GEMM_BLOCKS, 256, 0, stream>>>((const unsigned short*)aggb, wt,           b1, dinv, (void*)yB, N);
  k_spmm<<<spmm_grid, 256, 0, stream>>>(yB, offs, dinv, meta, aggb, N);
  k_gemm<true ><<<GEMM_BLOCKS, 256, 0, stream>>>((const unsigned short*)aggb, wt + 16384,   b2, dinv, (void*)yA, N);
  k_spmm<<<spmm_grid, 256, 0, stream>>>(yA, offs, dinv, meta, aggb, N);
  k_gemm<false><<<GEMM_BLOCKS, 256, 0, stream>>>((const unsigned short*)aggb, wt + 2*16384, b3, dinv, (void*)hbuf, N);

  k_pool <<<NGRAPH*POOL_S, 128, 0, stream>>>((const unsigned int*)hbuf, batch, part, N);
  k_final<<<NGRAPH, 128, 0, stream>>>(part, batch, Wl, bl, out, N);
}